// Round 8
// baseline (3553.032 us; speedup 1.0000x reference)
//
#include <hip/hip_runtime.h>
#include <math.h>

#define EPS 1e-5f
#define NBLK 384
#define NTHR 256
#define GSTRIDE (NBLK * NTHR)

struct Params {
    const float *x, *y;
    const float *blk_w1, *blk_ig, *blk_ib, *blk_w2_5, *blk_w2_7, *blk_w2_9;
    const float *blk_g, *blk_b, *blk_conv;
    const float *loc_w1, *loc_g, *loc_b, *loc_w2;
    const float *glb_w1, *glb_g, *glb_b, *glb_w2;
    const float *c3_w1, *c3_g, *c3_b, *c3_w2;
    const float *c4_w1, *c4_g, *c4_b, *c4_w2;
    const float *c5_w1, *c5_g, *c5_b, *c5_w2;
    const float *p1, *p2, *p3;
    const float *bn1g, *bn1b, *bn2g, *bn2b, *bn3g, *bn3b;
    const float *hg, *hb, *lw, *lb;
    float *out;
    float *bufA, *bufB, *t_raw, *o_raw;
    float *t_loc, *t_glb, *o_idn, *t3, *o3, *o5, *t4, *o6, *o8, *t5, *o9, *o11;
    float *feat1, *feat2, *stats;
    int *bar_cnt, *bar_gen;
};

__device__ inline void wave_red2(float& s1, float& s2){
    for (int off = 32; off; off >>= 1){
        s1 += __shfl_down(s1, off, 64);
        s2 += __shfl_down(s2, off, 64);
    }
}

// Grid-wide barrier: release/acquire at agent scope (flushes/invalidates
// per-XCD L2 so plain stores from phase N are visible in phase N+1).
__device__ inline void grid_barrier(int* cnt, int* gen){
    __syncthreads();
    if (threadIdx.x == 0){
        int g = __hip_atomic_load(gen, __ATOMIC_RELAXED, __HIP_MEMORY_SCOPE_AGENT);
        int prev = __hip_atomic_fetch_add(cnt, 1, __ATOMIC_ACQ_REL, __HIP_MEMORY_SCOPE_AGENT);
        if (prev == NBLK - 1){
            __hip_atomic_store(cnt, 0, __ATOMIC_RELAXED, __HIP_MEMORY_SCOPE_AGENT);
            __hip_atomic_fetch_add(gen, 1, __ATOMIC_ACQ_REL, __HIP_MEMORY_SCOPE_AGENT);
        } else {
            while (__hip_atomic_load(gen, __ATOMIC_ACQUIRE, __HIP_MEMORY_SCOPE_AGENT) == g){
                __builtin_amdgcn_s_sleep(4);
            }
        }
    }
    __syncthreads();
}

// ---------------------------------------------------------------------------
// conv1x1 (B=64): out[b,j,hw] = sum_c in[b,c,hw]*w[j,c]; stats optional.
// j wave-uniform (npos % 64 == 0, GSTRIDE % 64 == 0).
// ---------------------------------------------------------------------------
__device__ void dv_conv(const float* __restrict__ in, const float* __restrict__ w,
                        float* __restrict__ out, float* __restrict__ st,
                        int Cin, int Cout, int HW)
{
    int npos = 64 * HW;
    int total = Cout * npos;
    for (int item = blockIdx.x * NTHR + threadIdx.x; item < total; item += GSTRIDE){
        int j = item / npos, pos = item - j * npos;
        int b = pos / HW, hw = pos - b * HW;
        int ju = __builtin_amdgcn_readfirstlane(j);
        const float* ip = in + (size_t)b * Cin * HW + hw;
        const float* wr = w + (size_t)ju * Cin;
        float acc = 0.f;
        #pragma unroll 4
        for (int c = 0; c < Cin; ++c) acc += ip[c * HW] * wr[c];
        out[(size_t)b * Cout * HW + j * HW + hw] = acc;
        if (st){
            float s1 = acc, s2 = acc * acc;
            wave_red2(s1, s2);
            if ((threadIdx.x & 63) == 0){
                atomicAdd(&st[ju], s1);
                atomicAdd(&st[Cout + ju], s2);
            }
        }
    }
}

// ---------------------------------------------------------------------------
// Branch-1 involution unit: one block per (K, g, b). wk per position computed
// from LDS w2 (padded rows of 16, float4 reads) and applied to 15 channels
// held in acc registers.
// ---------------------------------------------------------------------------
template<int K>
__device__ void invol_unit(const float* __restrict__ in, const float* __restrict__ t_raw,
                           const float* __restrict__ st_t,
                           const float* __restrict__ tg, const float* __restrict__ tb,
                           const float* __restrict__ w2,
                           float* __restrict__ o_raw, float* __restrict__ st_o,
                           int b, int g, float* sm)
{
    constexpr int KK = K * K, P = (K - 1) / 2;
    float* in_s = sm;                 // 3375
    float* w2p  = sm + 3375;          // KK*16 <= 1296
    float* scb  = sm + 3375 + 1296;   // 15
    float* shb  = scb + 15;           // 15
    int tid = threadIdx.x;

    __syncthreads();
    if (tid < 15){
        const float invN = 1.f / 14400.f;
        float mean = st_t[tid] * invN;
        float var  = st_t[15 + tid] * invN - mean * mean;
        float s = tg[tid] * rsqrtf(var + EPS);
        scb[tid] = s; shb[tid] = tb[tid] - mean * s;
    }
    const float* w2g = w2 + (size_t)g * KK * 15;
    for (int i = tid; i < KK * 16; i += NTHR){
        int r = i >> 4, j = i & 15;
        w2p[i] = (j < 15) ? w2g[r * 15 + j] : 0.f;
    }
    const float* inb = in + (size_t)b * 6750 + (size_t)g * 3375;
    for (int i = tid; i < 3375; i += NTHR) in_s[i] = inb[i];
    __syncthreads();

    bool act = tid < 225;
    int p = act ? tid : 224;
    int h = p / 15, w = p - h * 15;

    float treg[16];
    const float* trb = t_raw + (size_t)b * 3375 + p;
    #pragma unroll
    for (int j = 0; j < 15; ++j){
        float v = trb[j * 225] * scb[j] + shb[j];
        treg[j] = v > 0.f ? v : 0.f;
    }
    treg[15] = 0.f;

    float acc[15];
    #pragma unroll
    for (int cc = 0; cc < 15; ++cc) acc[cc] = 0.f;

    #pragma unroll 1
    for (int kk = 0; kk < KK; ++kk){
        int ki = kk / K, kj = kk - ki * K;
        int hh = h + ki - P, ww = w + kj - P;
        bool ok = ((unsigned)hh < 15u) && ((unsigned)ww < 15u);
        const float4* w4 = (const float4*)(w2p + (kk << 4));
        float4 A = w4[0], B = w4[1], C = w4[2], D = w4[3];
        float wkv = A.x*treg[0] + A.y*treg[1] + A.z*treg[2] + A.w*treg[3]
                  + B.x*treg[4] + B.y*treg[5] + B.z*treg[6] + B.w*treg[7]
                  + C.x*treg[8] + C.y*treg[9] + C.z*treg[10] + C.w*treg[11]
                  + D.x*treg[12] + D.y*treg[13] + D.z*treg[14];
        float sc2 = ok ? wkv : 0.f;
        int offr = ok ? hh * 15 + ww : 0;
        #pragma unroll
        for (int cc = 0; cc < 15; ++cc) acc[cc] += sc2 * in_s[cc * 225 + offr];
    }

    float* ob = o_raw + (size_t)b * 6750 + (size_t)g * 3375;
    #pragma unroll 1
    for (int cc = 0; cc < 15; ++cc){
        float val = act ? acc[cc] : 0.f;
        if (act) ob[cc * 225 + p] = val;
        float s1 = val, s2 = val * val;
        wave_red2(s1, s2);
        if ((tid & 63) == 0){
            atomicAdd(&st_o[g * 15 + cc], s1);
            atomicAdd(&st_o[30 + g * 15 + cc], s2);
        }
    }
}

__device__ void dv_invol_b1(const Params& P, const float* cur, int bi, float* sm)
{
    const float* ig = P.blk_ig + bi * 45;
    const float* ib = P.blk_ib + bi * 45;
    const float* st_t = P.stats + bi * 90;
    float* st_o = P.stats + 270 + bi * 180;
    int u = blockIdx.x;
    if (u >= 384) return;
    int ks = u / 128, rem = u - ks * 128;
    int g = rem >> 6, b = rem & 63;
    if (ks == 0)
        invol_unit<5>(cur, P.t_raw,          st_t,      ig,      ib,      P.blk_w2_5 + bi * 750,
                      P.o_raw,          st_o,       b, g, sm);
    else if (ks == 1)
        invol_unit<7>(cur, P.t_raw + 216000, st_t + 30, ig + 15, ib + 15, P.blk_w2_7 + bi * 1470,
                      P.o_raw + 432000, st_o + 60,  b, g, sm);
    else
        invol_unit<9>(cur, P.t_raw + 432000, st_t + 60, ig + 30, ib + 30, P.blk_w2_9 + bi * 2430,
                      P.o_raw + 864000, st_o + 120, b, g, sm);
}

// ---------------------------------------------------------------------------
// Branch-1 block end.
// ---------------------------------------------------------------------------
__device__ void dv_blockend(const Params& P, int bi, const float* oldout, float* newout, float* sm)
{
    float* sc = sm; float* sh = sm + 90;
    const float* st_o = P.stats + 270 + bi * 180;
    const float* g = P.blk_g + bi * 90;
    const float* bb = P.blk_b + bi * 90;
    const float* conv = P.blk_conv + bi * 2700;
    __syncthreads();
    if (threadIdx.x < 90){
        int ii = threadIdx.x / 30, cc = threadIdx.x - ii * 30;
        const float* st = st_o + ii * 60;
        const float invN = 1.f / 14400.f;
        float mean = st[cc] * invN;
        float var = st[30 + cc] * invN - mean * mean;
        float s = g[threadIdx.x] * rsqrtf(var + EPS);
        sc[threadIdx.x] = s; sh[threadIdx.x] = bb[threadIdx.x] - mean * s;
    }
    __syncthreads();
    for (int item = blockIdx.x * NTHR + threadIdx.x; item < 432000; item += GSTRIDE){
        int c = item / 14400, pos = item - c * 14400;
        int b = pos / 225, hw = pos - b * 225;
        int cu = __builtin_amdgcn_readfirstlane(c);
        float acc = oldout[(size_t)b * 6750 + c * 225 + hw];
        const float* cr = conv + cu * 90;
        #pragma unroll
        for (int ii = 0; ii < 3; ++ii){
            const float* op = P.o_raw + ii * 432000 + (size_t)b * 6750 + hw;
            #pragma unroll 6
            for (int cc = 0; cc < 30; ++cc){
                float v = op[cc * 225] * sc[ii * 30 + cc] + sh[ii * 30 + cc];
                v = v > 0.f ? v : 0.f;
                acc += v * cr[ii * 30 + cc];
            }
        }
        newout[(size_t)b * 6750 + c * 225 + hw] = acc;
    }
}

// ---------------------------------------------------------------------------
// Cross-attention front: o_idn = y * (loc(y) + glb(y)).
// ---------------------------------------------------------------------------
__device__ void dv_crossatt(const Params& P, float* sm)
{
    float* lsc = sm; float* lsh = sm + 102; float* gsc = sm + 204; float* gsh = sm + 306;
    const float* s_tloc = P.stats + 810;
    const float* s_tglb = P.stats + 1014;
    __syncthreads();
    const float invN = 1.f / 576.f;
    for (int j = threadIdx.x; j < 102; j += NTHR){
        float m1 = s_tloc[j] * invN;
        float v1 = s_tloc[102 + j] * invN - m1 * m1;
        float a1 = P.loc_g[j] * rsqrtf(v1 + EPS);
        lsc[j] = a1; lsh[j] = P.loc_b[j] - m1 * a1;
        float m2 = s_tglb[j] * invN;
        float v2 = s_tglb[102 + j] * invN - m2 * m2;
        float a2 = P.glb_g[j] * rsqrtf(v2 + EPS);
        gsc[j] = a2; gsh[j] = P.glb_b[j] - m2 * a2;
    }
    __syncthreads();
    for (int item = blockIdx.x * NTHR + threadIdx.x; item < 117504; item += GSTRIDE){
        int c = item / 576, pos = item - c * 576;
        int b = pos / 9, hw = pos - b * 9;
        int h = hw / 3, w = hw - h * 3;
        int cu = __builtin_amdgcn_readfirstlane(c);
        const float* tl = P.t_loc + (size_t)b * 918 + hw;
        const float* tg_ = P.t_glb + (size_t)b * 918 + hw;
        const float* wl = P.loc_w2 + (size_t)cu * 918;
        float wk[9];
        #pragma unroll
        for (int kk = 0; kk < 9; ++kk) wk[kk] = 0.f;
        #pragma unroll 1
        for (int j = 0; j < 102; ++j){
            float a = tl[j * 9] * lsc[j] + lsh[j];
            a = a > 0.f ? a : 0.f;
            float g2 = tg_[j * 9] * gsc[j] + gsh[j];
            g2 = g2 > 0.f ? g2 : 0.f;
            #pragma unroll
            for (int kk = 0; kk < 9; ++kk)
                wk[kk] += a * wl[kk * 102 + j] + g2 * P.glb_w2[kk * 102 + j];
        }
        const float* pb = P.y + (size_t)b * 1836 + c * 9;
        float acc = 0.f;
        #pragma unroll
        for (int ki = 0; ki < 3; ++ki){
            int hh = h + ki - 1;
            bool hok = (unsigned)hh < 3u;
            #pragma unroll
            for (int kj = 0; kj < 3; ++kj){
                int ww = w + kj - 1;
                bool ok = hok && ((unsigned)ww < 3u);
                float v = ok ? pb[hh * 3 + ww] : 0.f;
                acc += wk[ki * 3 + kj] * v;
            }
        }
        P.o_idn[(size_t)b * 1836 + c * 9 + hw] = pb[hw] * acc;
    }
}

// ---------------------------------------------------------------------------
// groups==1 involution (wkgen + apply + stats), k=3.
// ---------------------------------------------------------------------------
__device__ void dv_invol3(const float* __restrict__ pin, const float* __restrict__ t_raw,
                          const float* __restrict__ st_t,
                          const float* __restrict__ tg, const float* __restrict__ tb,
                          const float* __restrict__ w2,
                          float* __restrict__ out, float* __restrict__ ost,
                          int C, int Ct, float* sm)
{
    float* tsc = sm; float* tsh = sm + 128;
    __syncthreads();
    const float invN = 1.f / 576.f;
    for (int j = threadIdx.x; j < Ct; j += NTHR){
        float mean = st_t[j] * invN;
        float var  = st_t[Ct + j] * invN - mean * mean;
        float s = tg[j] * rsqrtf(var + EPS);
        tsc[j] = s; tsh[j] = tb[j] - mean * s;
    }
    __syncthreads();
    for (int item = blockIdx.x * NTHR + threadIdx.x; item < C * 576; item += GSTRIDE){
        int c = item / 576, pos = item - c * 576;
        int b = pos / 9, hw = pos - b * 9;
        int h = hw / 3, w = hw - h * 3;
        const float* tp = t_raw + (size_t)b * Ct * 9 + hw;
        float wk[9];
        #pragma unroll
        for (int kk = 0; kk < 9; ++kk) wk[kk] = 0.f;
        #pragma unroll 1
        for (int j = 0; j < Ct; ++j){
            float t = tp[j * 9] * tsc[j] + tsh[j];
            t = t > 0.f ? t : 0.f;
            #pragma unroll
            for (int kk = 0; kk < 9; ++kk) wk[kk] += t * w2[kk * Ct + j];
        }
        const float* pb = pin + (size_t)b * C * 9 + c * 9;
        float acc = 0.f;
        #pragma unroll
        for (int ki = 0; ki < 3; ++ki){
            int hh = h + ki - 1;
            bool hok = (unsigned)hh < 3u;
            #pragma unroll
            for (int kj = 0; kj < 3; ++kj){
                int ww = w + kj - 1;
                bool ok = hok && ((unsigned)ww < 3u);
                float v = ok ? pb[hh * 3 + ww] : 0.f;
                acc += wk[ki * 3 + kj] * v;
            }
        }
        out[(size_t)b * C * 9 + c * 9 + hw] = acc;
        float s1 = acc, s2 = acc * acc;
        wave_red2(s1, s2);
        if ((threadIdx.x & 63) == 0){
            int cu = __builtin_amdgcn_readfirstlane(c);
            atomicAdd(&ost[cu], s1);
            atomicAdd(&ost[C + cu], s2);
        }
    }
}

// ---------------------------------------------------------------------------
// BN+ReLU(+residual) -> conv1x1.
// ---------------------------------------------------------------------------
__device__ void dv_bnconv(const float* __restrict__ in, const float* __restrict__ st,
                          const float* __restrict__ g, const float* __restrict__ bta,
                          const float* __restrict__ idn, const float* __restrict__ w,
                          float* __restrict__ out, int Cin, int Cout, float* sm)
{
    float* sc = sm; float* sh = sm + 256;
    __syncthreads();
    const float invN = 1.f / 576.f;
    for (int j = threadIdx.x; j < Cin; j += NTHR){
        float mean = st[j] * invN;
        float var = st[Cin + j] * invN - mean * mean;
        float s = g[j] * rsqrtf(var + EPS);
        sc[j] = s; sh[j] = bta[j] - mean * s;
    }
    __syncthreads();
    for (int item = blockIdx.x * NTHR + threadIdx.x; item < Cout * 576; item += GSTRIDE){
        int j = item / 576, pos = item - j * 576;
        int b = pos / 9, hw = pos - b * 9;
        int ju = __builtin_amdgcn_readfirstlane(j);
        const float* ip = in + (size_t)b * Cin * 9 + hw;
        const float* ir = idn ? idn + (size_t)b * Cin * 9 + hw : nullptr;
        const float* wr = w + (size_t)ju * Cin;
        float acc = 0.f;
        #pragma unroll 4
        for (int c = 0; c < Cin; ++c){
            float v = ip[c * 9] * sc[c] + sh[c];
            v = v > 0.f ? v : 0.f;
            if (ir) v += ir[c * 9];
            acc += v * wr[c];
        }
        out[(size_t)b * Cout * 9 + j * 9 + hw] = acc;
    }
}

// ---------------------------------------------------------------------------
// GlobalCovPooling (block b < 64). Faithful incl. ELEMENTWISE Y-update.
// ---------------------------------------------------------------------------
template<int C, int N>
__device__ void dv_covpool(const float* __restrict__ in, float* __restrict__ feat, float* sm)
{
    if (blockIdx.x >= 64) return;
    constexpr int CC = C * C;
    float* X = sm;
    float* Ybuf = sm + N * C;
    float* Mbuf = Ybuf + CC;
    float* Zbuf = Mbuf + CC;
    float* Z2buf = Zbuf + CC;
    float* mu = Z2buf + CC;
    float* scal = mu + C;
    int b = blockIdx.x, tid = threadIdx.x;
    const float* ib = in + (size_t)b * C * N;
    __syncthreads();
    for (int i = tid; i < N * C; i += NTHR){
        int n = i / C, c = i - n * C;
        X[i] = ib[(size_t)c * N + n];
    }
    __syncthreads();
    if (tid < C){
        float s = 0.f;
        #pragma unroll 5
        for (int n = 0; n < N; ++n) s += X[n * C + tid];
        mu[tid] = s / (float)N;
    }
    __syncthreads();
    for (int i = tid; i < CC; i += NTHR){
        int c = i / C, d = i - c * C;
        float s = 0.f;
        #pragma unroll 5
        for (int n = 0; n < N; ++n) s += X[n * C + c] * X[n * C + d];
        Ybuf[i] = s / (float)N - mu[c] * mu[d];
    }
    __syncthreads();
    if (tid == 0){
        float tr = 0.f;
        for (int c = 0; c < C; ++c) tr += Ybuf[c * C + c];
        scal[0] = 1.f / tr;
    }
    __syncthreads();
    for (int i = tid; i < CC; i += NTHR){
        int c = i / C, d = i - c * C;
        Ybuf[i] *= scal[0];
        Zbuf[i] = (c == d) ? 1.f : 0.f;
    }
    __syncthreads();
    float* zs = Zbuf; float* zd = Z2buf;
    for (int it = 0; it < 6; ++it){
        for (int i = tid; i < CC; i += NTHR){
            int c = i / C, d = i - c * C;
            float s = 0.f;
            #pragma unroll 6
            for (int e = 0; e < C; ++e) s += zs[c * C + e] * Ybuf[e * C + d];
            Mbuf[i] = ((c == d) ? 3.f : 0.f) - s;
        }
        __syncthreads();
        for (int i = tid; i < CC; i += NTHR){
            int c = i / C, d = i - c * C;
            float s = 0.f;
            #pragma unroll 6
            for (int e = 0; e < C; ++e) s += Mbuf[c * C + e] * zs[e * C + d];
            zd[i] = 0.5f * s;
        }
        for (int i = tid; i < CC; i += NTHR) Ybuf[i] *= 0.5f * Mbuf[i];   // elementwise, as in source
        __syncthreads();
        float* t = zs; zs = zd; zd = t;
    }
    if (tid == 0){
        float tr = 0.f;
        for (int c = 0; c < C; ++c) tr += Ybuf[c * C + c];
        scal[1] = sqrtf(tr);
    }
    __syncthreads();
    if (tid < C){
        float s = 0.f;
        #pragma unroll 6
        for (int c = 0; c < C; ++c) s += Ybuf[c * C + tid];
        feat[(size_t)b * C + tid] = scal[1] * s / (float)C;
    }
}

// ---------------------------------------------------------------------------
// Head (block 0).
// ---------------------------------------------------------------------------
__device__ void dv_head(const Params& P, float* sm)
{
    if (blockIdx.x != 0) return;
    float* f = sm;   // 46*64
    int tid = threadIdx.x;
    __syncthreads();
    for (int i = tid; i < 46 * 64; i += NTHR){
        int ch = i / 64, b = i - ch * 64;
        f[i] = ch < 30 ? P.feat1[b * 30 + ch] : P.feat2[b * 16 + (ch - 30)];
    }
    __syncthreads();
    if (tid < 46){
        float s = 0.f, s2 = 0.f;
        for (int b = 0; b < 64; ++b){ float v = f[tid * 64 + b]; s += v; s2 += v * v; }
        float mean = s / 64.f, var = s2 / 64.f - mean * mean;
        float sc = P.hg[tid] * rsqrtf(var + EPS), sh = P.hb[tid] - mean * sc;
        for (int b = 0; b < 64; ++b){
            float v = f[tid * 64 + b] * sc + sh;
            f[tid * 64 + b] = v > 0.f ? v : 0.f;
        }
    }
    __syncthreads();
    if (tid < 64){
        int b = tid;
        float l[16];
        float m = -1e30f;
        for (int o = 0; o < 16; ++o){
            float a = P.lb[o];
            for (int ch = 0; ch < 46; ++ch) a += f[ch * 64 + b] * P.lw[o * 46 + ch];
            l[o] = a; m = fmaxf(m, a);
        }
        float se = 0.f;
        for (int o = 0; o < 16; ++o){ l[o] = expf(l[o] - m); se += l[o]; }
        float inv = 1.f / se;
        for (int o = 0; o < 16; ++o) P.out[b * 16 + o] = l[o] * inv;
    }
}

// ---------------------------------------------------------------------------
// The megakernel: 13 phases, 12 grid barriers. Branch-1 and branch-2 steps
// share phases (independent chains run concurrently).
// ---------------------------------------------------------------------------
__global__ __launch_bounds__(NTHR, 2)
void meganet(Params P)
{
    __shared__ float sm[10384];
    int* cnt = P.bar_cnt; int* gen = P.bar_gen;

    float* st_t0 = P.stats;            // bi*90
    float* s_tloc = P.stats + 810;
    float* s_tglb = P.stats + 1014;
    float* s_t3 = P.stats + 1218;
    float* s_o3 = P.stats + 1422;
    float* s_t4 = P.stats + 1830;
    float* s_o6 = P.stats + 1932;
    float* s_t5 = P.stats + 2136;
    float* s_o9 = P.stats + 2186;

    // Phase 0: b1.conv1(bi0) ; b2.conv_dual
    for (int s = 0; s < 3; ++s)
        dv_conv(P.x, P.blk_w1 + s * 450, P.t_raw + s * 216000, st_t0 + s * 30, 30, 15, 225);
    dv_conv(P.y, P.loc_w1, P.t_loc, s_tloc, 204, 102, 9);
    dv_conv(P.y, P.glb_w1, P.t_glb, s_tglb, 204, 102, 9);
    grid_barrier(cnt, gen);
    // Phase 1: b1.invol(bi0) ; b2.crossatt
    dv_invol_b1(P, P.x, 0, sm);
    dv_crossatt(P, sm);
    grid_barrier(cnt, gen);
    // Phase 2: b1.blockend(bi0) x->bufA ; b2.conv c3
    dv_blockend(P, 0, P.x, P.bufA, sm);
    dv_conv(P.o_idn, P.c3_w1, P.t3, s_t3, 204, 102, 9);
    grid_barrier(cnt, gen);
    // Phase 3: b1.conv1(bi1) ; b2.invol3 c3
    for (int s = 0; s < 3; ++s)
        dv_conv(P.bufA, P.blk_w1 + 1350 + s * 450, P.t_raw + s * 216000, st_t0 + 90 + s * 30, 30, 15, 225);
    dv_invol3(P.o_idn, P.t3, s_t3, P.c3_g, P.c3_b, P.c3_w2, P.o3, s_o3, 204, 102, sm);
    grid_barrier(cnt, gen);
    // Phase 4: b1.invol(bi1) ; b2.bnconv p1 -> o5
    dv_invol_b1(P, P.bufA, 1, sm);
    dv_bnconv(P.o3, s_o3, P.bn1g, P.bn1b, P.o_idn, P.p1, P.o5, 204, 102, sm + 4800);
    grid_barrier(cnt, gen);
    // Phase 5: b1.blockend(bi1) bufA->bufB ; b2.conv c4
    dv_blockend(P, 1, P.bufA, P.bufB, sm);
    dv_conv(P.o5, P.c4_w1, P.t4, s_t4, 102, 51, 9);
    grid_barrier(cnt, gen);
    // Phase 6: b1.conv1(bi2) ; b2.invol3 c4
    for (int s = 0; s < 3; ++s)
        dv_conv(P.bufB, P.blk_w1 + 2700 + s * 450, P.t_raw + s * 216000, st_t0 + 180 + s * 30, 30, 15, 225);
    dv_invol3(P.o5, P.t4, s_t4, P.c4_g, P.c4_b, P.c4_w2, P.o6, s_o6, 102, 51, sm);
    grid_barrier(cnt, gen);
    // Phase 7: b1.invol(bi2) ; b2.bnconv p2 -> o8
    dv_invol_b1(P, P.bufB, 2, sm);
    dv_bnconv(P.o6, s_o6, P.bn2g, P.bn2b, nullptr, P.p2, P.o8, 102, 51, sm + 4800);
    grid_barrier(cnt, gen);
    // Phase 8: b1.blockend(bi2) bufB->bufA ; b2.conv c5
    dv_blockend(P, 2, P.bufB, P.bufA, sm);
    dv_conv(P.o8, P.c5_w1, P.t5, s_t5, 51, 25, 9);
    grid_barrier(cnt, gen);
    // Phase 9: b1.covpool30 ; b2.invol3 c5
    dv_invol3(P.o8, P.t5, s_t5, P.c5_g, P.c5_b, P.c5_w2, P.o9, s_o9, 51, 25, sm + 6750 + 3600);
    dv_covpool<30, 225>(P.bufA, P.feat1, sm);
    grid_barrier(cnt, gen);
    // Phase 10: b2.bnconv p3 -> o11
    dv_bnconv(P.o9, s_o9, P.bn3g, P.bn3b, P.o8, P.p3, P.o11, 51, 16, sm);
    grid_barrier(cnt, gen);
    // Phase 11: b2.covpool16
    dv_covpool<16, 9>(P.o11, P.feat2, sm);
    grid_barrier(cnt, gen);
    // Phase 12: head
    dv_head(P, sm);
}

extern "C" void kernel_launch(void* const* d_in, const int* in_sizes, int n_in,
                              void* d_out, int out_size, void* d_ws, size_t ws_size,
                              hipStream_t stream)
{
    (void)in_sizes; (void)n_in; (void)out_size; (void)ws_size;
    Params P;
    P.x = (const float*)d_in[0];   P.y = (const float*)d_in[1];
    P.blk_w1 = (const float*)d_in[2]; P.blk_ig = (const float*)d_in[3]; P.blk_ib = (const float*)d_in[4];
    P.blk_w2_5 = (const float*)d_in[5]; P.blk_w2_7 = (const float*)d_in[6]; P.blk_w2_9 = (const float*)d_in[7];
    P.blk_g = (const float*)d_in[8]; P.blk_b = (const float*)d_in[9]; P.blk_conv = (const float*)d_in[10];
    P.loc_w1 = (const float*)d_in[11]; P.loc_g = (const float*)d_in[12]; P.loc_b = (const float*)d_in[13]; P.loc_w2 = (const float*)d_in[14];
    P.glb_w1 = (const float*)d_in[15]; P.glb_g = (const float*)d_in[16]; P.glb_b = (const float*)d_in[17]; P.glb_w2 = (const float*)d_in[18];
    P.c3_w1 = (const float*)d_in[19]; P.c3_g = (const float*)d_in[20]; P.c3_b = (const float*)d_in[21]; P.c3_w2 = (const float*)d_in[22];
    P.c4_w1 = (const float*)d_in[23]; P.c4_g = (const float*)d_in[24]; P.c4_b = (const float*)d_in[25]; P.c4_w2 = (const float*)d_in[26];
    P.c5_w1 = (const float*)d_in[27]; P.c5_g = (const float*)d_in[28]; P.c5_b = (const float*)d_in[29]; P.c5_w2 = (const float*)d_in[30];
    P.p1 = (const float*)d_in[31]; P.p2 = (const float*)d_in[32]; P.p3 = (const float*)d_in[33];
    P.bn1g = (const float*)d_in[34]; P.bn1b = (const float*)d_in[35];
    P.bn2g = (const float*)d_in[36]; P.bn2b = (const float*)d_in[37];
    P.bn3g = (const float*)d_in[38]; P.bn3b = (const float*)d_in[39];
    P.hg = (const float*)d_in[40]; P.hb = (const float*)d_in[41];
    P.lw = (const float*)d_in[42]; P.lb = (const float*)d_in[43];
    P.out = (float*)d_out;

    float* ws = (float*)d_ws;
    size_t off = 0;
    auto alloc = [&](size_t n){ float* p = ws + off; off += n; return p; };
    P.bufA  = alloc(432000);
    P.bufB  = alloc(432000);
    P.t_raw = alloc(648000);
    P.o_raw = alloc(1296000);
    P.t_loc = alloc(58752);
    P.t_glb = alloc(58752);
    P.o_idn = alloc(117504);
    P.t3    = alloc(58752);
    P.o3    = alloc(117504);
    P.o5    = alloc(58752);
    P.t4    = alloc(29376);
    P.o6    = alloc(58752);
    P.o8    = alloc(29376);
    P.t5    = alloc(14400);
    P.o9    = alloc(29376);
    P.o11   = alloc(9216);
    P.feat1 = alloc(1920);
    P.feat2 = alloc(1024);
    P.stats = alloc(2288);
    float* barmem = alloc(4);
    P.bar_cnt = (int*)barmem;
    P.bar_gen = (int*)(barmem + 1);

    // zero stats + barrier state (d_ws is poisoned 0xAA before every call)
    hipMemsetAsync(P.stats, 0, (2288 + 4) * sizeof(float), stream);

    meganet<<<NBLK, NTHR, 0, stream>>>(P);
}

// Round 9
// 1648.438 us; speedup vs baseline: 2.1554x; 2.1554x over previous
//
#include <hip/hip_runtime.h>
#include <math.h>

#define EPS 1e-5f
#define NBLK 384
#define NTHR 256
#define GSTRIDE (NBLK * NTHR)

struct Params {
    const float *x, *y;
    const float *blk_w1, *blk_ig, *blk_ib, *blk_w2_5, *blk_w2_7, *blk_w2_9;
    const float *blk_g, *blk_b, *blk_conv;
    const float *loc_w1, *loc_g, *loc_b, *loc_w2;
    const float *glb_w1, *glb_g, *glb_b, *glb_w2;
    const float *c3_w1, *c3_g, *c3_b, *c3_w2;
    const float *c4_w1, *c4_g, *c4_b, *c4_w2;
    const float *c5_w1, *c5_g, *c5_b, *c5_w2;
    const float *p1, *p2, *p3;
    const float *bn1g, *bn1b, *bn2g, *bn2b, *bn3g, *bn3b;
    const float *hg, *hb, *lw, *lb;
    float *out;
    float *bufA, *bufB, *t_raw, *o_raw;
    float *t_loc, *t_glb, *o_idn, *t3, *o3, *o5, *t4, *o6, *o8, *t5, *o9, *o11;
    float *feat1, *feat2, *stats;
    int *bar_cnt;
};

__device__ inline void wave_red2(float& s1, float& s2){
    for (int off = 32; off; off >>= 1){
        s1 += __shfl_down(s1, off, 64);
        s2 += __shfl_down(s2, off, 64);
    }
}

// Grid barrier, k-th use (k = 1,2,...): monotonic arrival counter (no reset,
// no reset-race), RELAXED spin (agent-scope relaxed atomic loads read the
// coherence point WITHOUT invalidating L1/L2 -- the R8 acquire-spin emitted an
// L2 invalidate per poll, thrashing all caches). Exactly one release/acquire
// __threadfence() pair per block per barrier handles bulk-data visibility.
__device__ inline void grid_barrier(int* cnt, int k){
    __syncthreads();
    if (threadIdx.x == 0){
        __threadfence();   // release: write back this XCD's dirty L2
        __hip_atomic_fetch_add(cnt, 1, __ATOMIC_RELAXED, __HIP_MEMORY_SCOPE_AGENT);
        int target = NBLK * k;
        while (__hip_atomic_load(cnt, __ATOMIC_RELAXED, __HIP_MEMORY_SCOPE_AGENT) < target){
            __builtin_amdgcn_s_sleep(8);
        }
        __threadfence();   // acquire: invalidate stale L1/L2
    }
    __syncthreads();
}

// ---------------------------------------------------------------------------
// conv1x1 (B=64): out[b,j,hw] = sum_c in[b,c,hw]*w[j,c]; stats optional.
// j wave-uniform (npos % 64 == 0, GSTRIDE % 64 == 0).
// ---------------------------------------------------------------------------
__device__ void dv_conv(const float* __restrict__ in, const float* __restrict__ w,
                        float* __restrict__ out, float* __restrict__ st,
                        int Cin, int Cout, int HW)
{
    int npos = 64 * HW;
    int total = Cout * npos;
    for (int item = blockIdx.x * NTHR + threadIdx.x; item < total; item += GSTRIDE){
        int j = item / npos, pos = item - j * npos;
        int b = pos / HW, hw = pos - b * HW;
        int ju = __builtin_amdgcn_readfirstlane(j);
        const float* ip = in + (size_t)b * Cin * HW + hw;
        const float* wr = w + (size_t)ju * Cin;
        float acc = 0.f;
        #pragma unroll 4
        for (int c = 0; c < Cin; ++c) acc += ip[c * HW] * wr[c];
        out[(size_t)b * Cout * HW + j * HW + hw] = acc;
        if (st){
            float s1 = acc, s2 = acc * acc;
            wave_red2(s1, s2);
            if ((threadIdx.x & 63) == 0){
                atomicAdd(&st[ju], s1);
                atomicAdd(&st[Cout + ju], s2);
            }
        }
    }
}

// ---------------------------------------------------------------------------
// Branch-1 involution unit: one block per (K, g, b).
// ---------------------------------------------------------------------------
template<int K>
__device__ void invol_unit(const float* __restrict__ in, const float* __restrict__ t_raw,
                           const float* __restrict__ st_t,
                           const float* __restrict__ tg, const float* __restrict__ tb,
                           const float* __restrict__ w2,
                           float* __restrict__ o_raw, float* __restrict__ st_o,
                           int b, int g, float* sm)
{
    constexpr int KK = K * K, P = (K - 1) / 2;
    float* in_s = sm;                 // 3375
    float* w2p  = sm + 3375;          // KK*16 <= 1296
    float* scb  = sm + 3375 + 1296;   // 15
    float* shb  = scb + 15;           // 15
    int tid = threadIdx.x;

    __syncthreads();
    if (tid < 15){
        const float invN = 1.f / 14400.f;
        float mean = st_t[tid] * invN;
        float var  = st_t[15 + tid] * invN - mean * mean;
        float s = tg[tid] * rsqrtf(var + EPS);
        scb[tid] = s; shb[tid] = tb[tid] - mean * s;
    }
    const float* w2g = w2 + (size_t)g * KK * 15;
    for (int i = tid; i < KK * 16; i += NTHR){
        int r = i >> 4, j = i & 15;
        w2p[i] = (j < 15) ? w2g[r * 15 + j] : 0.f;
    }
    const float* inb = in + (size_t)b * 6750 + (size_t)g * 3375;
    for (int i = tid; i < 3375; i += NTHR) in_s[i] = inb[i];
    __syncthreads();

    bool act = tid < 225;
    int p = act ? tid : 224;
    int h = p / 15, w = p - h * 15;

    float treg[16];
    const float* trb = t_raw + (size_t)b * 3375 + p;
    #pragma unroll
    for (int j = 0; j < 15; ++j){
        float v = trb[j * 225] * scb[j] + shb[j];
        treg[j] = v > 0.f ? v : 0.f;
    }
    treg[15] = 0.f;

    float acc[15];
    #pragma unroll
    for (int cc = 0; cc < 15; ++cc) acc[cc] = 0.f;

    #pragma unroll 1
    for (int kk = 0; kk < KK; ++kk){
        int ki = kk / K, kj = kk - ki * K;
        int hh = h + ki - P, ww = w + kj - P;
        bool ok = ((unsigned)hh < 15u) && ((unsigned)ww < 15u);
        const float4* w4 = (const float4*)(w2p + (kk << 4));
        float4 A = w4[0], B = w4[1], C = w4[2], D = w4[3];
        float wkv = A.x*treg[0] + A.y*treg[1] + A.z*treg[2] + A.w*treg[3]
                  + B.x*treg[4] + B.y*treg[5] + B.z*treg[6] + B.w*treg[7]
                  + C.x*treg[8] + C.y*treg[9] + C.z*treg[10] + C.w*treg[11]
                  + D.x*treg[12] + D.y*treg[13] + D.z*treg[14];
        float sc2 = ok ? wkv : 0.f;
        int offr = ok ? hh * 15 + ww : 0;
        #pragma unroll
        for (int cc = 0; cc < 15; ++cc) acc[cc] += sc2 * in_s[cc * 225 + offr];
    }

    float* ob = o_raw + (size_t)b * 6750 + (size_t)g * 3375;
    #pragma unroll 1
    for (int cc = 0; cc < 15; ++cc){
        float val = act ? acc[cc] : 0.f;
        if (act) ob[cc * 225 + p] = val;
        float s1 = val, s2 = val * val;
        wave_red2(s1, s2);
        if ((tid & 63) == 0){
            atomicAdd(&st_o[g * 15 + cc], s1);
            atomicAdd(&st_o[30 + g * 15 + cc], s2);
        }
    }
}

__device__ void dv_invol_b1(const Params& P, const float* cur, int bi, float* sm)
{
    const float* ig = P.blk_ig + bi * 45;
    const float* ib = P.blk_ib + bi * 45;
    const float* st_t = P.stats + bi * 90;
    float* st_o = P.stats + 270 + bi * 180;
    int u = blockIdx.x;
    if (u >= 384) return;
    int ks = u / 128, rem = u - ks * 128;
    int g = rem >> 6, b = rem & 63;
    if (ks == 0)
        invol_unit<5>(cur, P.t_raw,          st_t,      ig,      ib,      P.blk_w2_5 + bi * 750,
                      P.o_raw,          st_o,       b, g, sm);
    else if (ks == 1)
        invol_unit<7>(cur, P.t_raw + 216000, st_t + 30, ig + 15, ib + 15, P.blk_w2_7 + bi * 1470,
                      P.o_raw + 432000, st_o + 60,  b, g, sm);
    else
        invol_unit<9>(cur, P.t_raw + 432000, st_t + 60, ig + 30, ib + 30, P.blk_w2_9 + bi * 2430,
                      P.o_raw + 864000, st_o + 120, b, g, sm);
}

// ---------------------------------------------------------------------------
// Branch-1 block end.
// ---------------------------------------------------------------------------
__device__ void dv_blockend(const Params& P, int bi, const float* oldout, float* newout, float* sm)
{
    float* sc = sm; float* sh = sm + 90;
    const float* st_o = P.stats + 270 + bi * 180;
    const float* g = P.blk_g + bi * 90;
    const float* bb = P.blk_b + bi * 90;
    const float* conv = P.blk_conv + bi * 2700;
    __syncthreads();
    if (threadIdx.x < 90){
        int ii = threadIdx.x / 30, cc = threadIdx.x - ii * 30;
        const float* st = st_o + ii * 60;
        const float invN = 1.f / 14400.f;
        float mean = st[cc] * invN;
        float var = st[30 + cc] * invN - mean * mean;
        float s = g[threadIdx.x] * rsqrtf(var + EPS);
        sc[threadIdx.x] = s; sh[threadIdx.x] = bb[threadIdx.x] - mean * s;
    }
    __syncthreads();
    for (int item = blockIdx.x * NTHR + threadIdx.x; item < 432000; item += GSTRIDE){
        int c = item / 14400, pos = item - c * 14400;
        int b = pos / 225, hw = pos - b * 225;
        int cu = __builtin_amdgcn_readfirstlane(c);
        float acc = oldout[(size_t)b * 6750 + c * 225 + hw];
        const float* cr = conv + cu * 90;
        #pragma unroll
        for (int ii = 0; ii < 3; ++ii){
            const float* op = P.o_raw + ii * 432000 + (size_t)b * 6750 + hw;
            #pragma unroll 6
            for (int cc = 0; cc < 30; ++cc){
                float v = op[cc * 225] * sc[ii * 30 + cc] + sh[ii * 30 + cc];
                v = v > 0.f ? v : 0.f;
                acc += v * cr[ii * 30 + cc];
            }
        }
        newout[(size_t)b * 6750 + c * 225 + hw] = acc;
    }
}

// ---------------------------------------------------------------------------
// Cross-attention front: o_idn = y * (loc(y) + glb(y)).
// ---------------------------------------------------------------------------
__device__ void dv_crossatt(const Params& P, float* sm)
{
    float* lsc = sm; float* lsh = sm + 102; float* gsc = sm + 204; float* gsh = sm + 306;
    const float* s_tloc = P.stats + 810;
    const float* s_tglb = P.stats + 1014;
    __syncthreads();
    const float invN = 1.f / 576.f;
    for (int j = threadIdx.x; j < 102; j += NTHR){
        float m1 = s_tloc[j] * invN;
        float v1 = s_tloc[102 + j] * invN - m1 * m1;
        float a1 = P.loc_g[j] * rsqrtf(v1 + EPS);
        lsc[j] = a1; lsh[j] = P.loc_b[j] - m1 * a1;
        float m2 = s_tglb[j] * invN;
        float v2 = s_tglb[102 + j] * invN - m2 * m2;
        float a2 = P.glb_g[j] * rsqrtf(v2 + EPS);
        gsc[j] = a2; gsh[j] = P.glb_b[j] - m2 * a2;
    }
    __syncthreads();
    for (int item = blockIdx.x * NTHR + threadIdx.x; item < 117504; item += GSTRIDE){
        int c = item / 576, pos = item - c * 576;
        int b = pos / 9, hw = pos - b * 9;
        int h = hw / 3, w = hw - h * 3;
        int cu = __builtin_amdgcn_readfirstlane(c);
        const float* tl = P.t_loc + (size_t)b * 918 + hw;
        const float* tg_ = P.t_glb + (size_t)b * 918 + hw;
        const float* wl = P.loc_w2 + (size_t)cu * 918;
        float wk[9];
        #pragma unroll
        for (int kk = 0; kk < 9; ++kk) wk[kk] = 0.f;
        #pragma unroll 1
        for (int j = 0; j < 102; ++j){
            float a = tl[j * 9] * lsc[j] + lsh[j];
            a = a > 0.f ? a : 0.f;
            float g2 = tg_[j * 9] * gsc[j] + gsh[j];
            g2 = g2 > 0.f ? g2 : 0.f;
            #pragma unroll
            for (int kk = 0; kk < 9; ++kk)
                wk[kk] += a * wl[kk * 102 + j] + g2 * P.glb_w2[kk * 102 + j];
        }
        const float* pb = P.y + (size_t)b * 1836 + c * 9;
        float acc = 0.f;
        #pragma unroll
        for (int ki = 0; ki < 3; ++ki){
            int hh = h + ki - 1;
            bool hok = (unsigned)hh < 3u;
            #pragma unroll
            for (int kj = 0; kj < 3; ++kj){
                int ww = w + kj - 1;
                bool ok = hok && ((unsigned)ww < 3u);
                float v = ok ? pb[hh * 3 + ww] : 0.f;
                acc += wk[ki * 3 + kj] * v;
            }
        }
        P.o_idn[(size_t)b * 1836 + c * 9 + hw] = pb[hw] * acc;
    }
}

// ---------------------------------------------------------------------------
// groups==1 involution (wkgen + apply + stats), k=3.
// ---------------------------------------------------------------------------
__device__ void dv_invol3(const float* __restrict__ pin, const float* __restrict__ t_raw,
                          const float* __restrict__ st_t,
                          const float* __restrict__ tg, const float* __restrict__ tb,
                          const float* __restrict__ w2,
                          float* __restrict__ out, float* __restrict__ ost,
                          int C, int Ct, float* sm)
{
    float* tsc = sm; float* tsh = sm + 128;
    __syncthreads();
    const float invN = 1.f / 576.f;
    for (int j = threadIdx.x; j < Ct; j += NTHR){
        float mean = st_t[j] * invN;
        float var  = st_t[Ct + j] * invN - mean * mean;
        float s = tg[j] * rsqrtf(var + EPS);
        tsc[j] = s; tsh[j] = tb[j] - mean * s;
    }
    __syncthreads();
    for (int item = blockIdx.x * NTHR + threadIdx.x; item < C * 576; item += GSTRIDE){
        int c = item / 576, pos = item - c * 576;
        int b = pos / 9, hw = pos - b * 9;
        int h = hw / 3, w = hw - h * 3;
        const float* tp = t_raw + (size_t)b * Ct * 9 + hw;
        float wk[9];
        #pragma unroll
        for (int kk = 0; kk < 9; ++kk) wk[kk] = 0.f;
        #pragma unroll 1
        for (int j = 0; j < Ct; ++j){
            float t = tp[j * 9] * tsc[j] + tsh[j];
            t = t > 0.f ? t : 0.f;
            #pragma unroll
            for (int kk = 0; kk < 9; ++kk) wk[kk] += t * w2[kk * Ct + j];
        }
        const float* pb = pin + (size_t)b * C * 9 + c * 9;
        float acc = 0.f;
        #pragma unroll
        for (int ki = 0; ki < 3; ++ki){
            int hh = h + ki - 1;
            bool hok = (unsigned)hh < 3u;
            #pragma unroll
            for (int kj = 0; kj < 3; ++kj){
                int ww = w + kj - 1;
                bool ok = hok && ((unsigned)ww < 3u);
                float v = ok ? pb[hh * 3 + ww] : 0.f;
                acc += wk[ki * 3 + kj] * v;
            }
        }
        out[(size_t)b * C * 9 + c * 9 + hw] = acc;
        float s1 = acc, s2 = acc * acc;
        wave_red2(s1, s2);
        if ((threadIdx.x & 63) == 0){
            int cu = __builtin_amdgcn_readfirstlane(c);
            atomicAdd(&ost[cu], s1);
            atomicAdd(&ost[C + cu], s2);
        }
    }
}

// ---------------------------------------------------------------------------
// BN+ReLU(+residual) -> conv1x1.
// ---------------------------------------------------------------------------
__device__ void dv_bnconv(const float* __restrict__ in, const float* __restrict__ st,
                          const float* __restrict__ g, const float* __restrict__ bta,
                          const float* __restrict__ idn, const float* __restrict__ w,
                          float* __restrict__ out, int Cin, int Cout, float* sm)
{
    float* sc = sm; float* sh = sm + 256;
    __syncthreads();
    const float invN = 1.f / 576.f;
    for (int j = threadIdx.x; j < Cin; j += NTHR){
        float mean = st[j] * invN;
        float var = st[Cin + j] * invN - mean * mean;
        float s = g[j] * rsqrtf(var + EPS);
        sc[j] = s; sh[j] = bta[j] - mean * s;
    }
    __syncthreads();
    for (int item = blockIdx.x * NTHR + threadIdx.x; item < Cout * 576; item += GSTRIDE){
        int j = item / 576, pos = item - j * 576;
        int b = pos / 9, hw = pos - b * 9;
        int ju = __builtin_amdgcn_readfirstlane(j);
        const float* ip = in + (size_t)b * Cin * 9 + hw;
        const float* ir = idn ? idn + (size_t)b * Cin * 9 + hw : nullptr;
        const float* wr = w + (size_t)ju * Cin;
        float acc = 0.f;
        #pragma unroll 4
        for (int c = 0; c < Cin; ++c){
            float v = ip[c * 9] * sc[c] + sh[c];
            v = v > 0.f ? v : 0.f;
            if (ir) v += ir[c * 9];
            acc += v * wr[c];
        }
        out[(size_t)b * Cout * 9 + j * 9 + hw] = acc;
    }
}

// ---------------------------------------------------------------------------
// GlobalCovPooling (block b < 64). Faithful incl. ELEMENTWISE Y-update.
// ---------------------------------------------------------------------------
template<int C, int N>
__device__ void dv_covpool(const float* __restrict__ in, float* __restrict__ feat, float* sm)
{
    if (blockIdx.x >= 64) return;
    constexpr int CC = C * C;
    float* X = sm;
    float* Ybuf = sm + N * C;
    float* Mbuf = Ybuf + CC;
    float* Zbuf = Mbuf + CC;
    float* Z2buf = Zbuf + CC;
    float* mu = Z2buf + CC;
    float* scal = mu + C;
    int b = blockIdx.x, tid = threadIdx.x;
    const float* ib = in + (size_t)b * C * N;
    __syncthreads();
    for (int i = tid; i < N * C; i += NTHR){
        int n = i / C, c = i - n * C;
        X[i] = ib[(size_t)c * N + n];
    }
    __syncthreads();
    if (tid < C){
        float s = 0.f;
        #pragma unroll 5
        for (int n = 0; n < N; ++n) s += X[n * C + tid];
        mu[tid] = s / (float)N;
    }
    __syncthreads();
    for (int i = tid; i < CC; i += NTHR){
        int c = i / C, d = i - c * C;
        float s = 0.f;
        #pragma unroll 5
        for (int n = 0; n < N; ++n) s += X[n * C + c] * X[n * C + d];
        Ybuf[i] = s / (float)N - mu[c] * mu[d];
    }
    __syncthreads();
    if (tid == 0){
        float tr = 0.f;
        for (int c = 0; c < C; ++c) tr += Ybuf[c * C + c];
        scal[0] = 1.f / tr;
    }
    __syncthreads();
    for (int i = tid; i < CC; i += NTHR){
        int c = i / C, d = i - c * C;
        Ybuf[i] *= scal[0];
        Zbuf[i] = (c == d) ? 1.f : 0.f;
    }
    __syncthreads();
    float* zs = Zbuf; float* zd = Z2buf;
    for (int it = 0; it < 6; ++it){
        for (int i = tid; i < CC; i += NTHR){
            int c = i / C, d = i - c * C;
            float s = 0.f;
            #pragma unroll 6
            for (int e = 0; e < C; ++e) s += zs[c * C + e] * Ybuf[e * C + d];
            Mbuf[i] = ((c == d) ? 3.f : 0.f) - s;
        }
        __syncthreads();
        for (int i = tid; i < CC; i += NTHR){
            int c = i / C, d = i - c * C;
            float s = 0.f;
            #pragma unroll 6
            for (int e = 0; e < C; ++e) s += Mbuf[c * C + e] * zs[e * C + d];
            zd[i] = 0.5f * s;
        }
        for (int i = tid; i < CC; i += NTHR) Ybuf[i] *= 0.5f * Mbuf[i];   // elementwise, as in source
        __syncthreads();
        float* t = zs; zs = zd; zd = t;
    }
    if (tid == 0){
        float tr = 0.f;
        for (int c = 0; c < C; ++c) tr += Ybuf[c * C + c];
        scal[1] = sqrtf(tr);
    }
    __syncthreads();
    if (tid < C){
        float s = 0.f;
        #pragma unroll 6
        for (int c = 0; c < C; ++c) s += Ybuf[c * C + tid];
        feat[(size_t)b * C + tid] = scal[1] * s / (float)C;
    }
}

// ---------------------------------------------------------------------------
// Head (block 0).
// ---------------------------------------------------------------------------
__device__ void dv_head(const Params& P, float* sm)
{
    if (blockIdx.x != 0) return;
    float* f = sm;   // 46*64
    int tid = threadIdx.x;
    __syncthreads();
    for (int i = tid; i < 46 * 64; i += NTHR){
        int ch = i / 64, b = i - ch * 64;
        f[i] = ch < 30 ? P.feat1[b * 30 + ch] : P.feat2[b * 16 + (ch - 30)];
    }
    __syncthreads();
    if (tid < 46){
        float s = 0.f, s2 = 0.f;
        for (int b = 0; b < 64; ++b){ float v = f[tid * 64 + b]; s += v; s2 += v * v; }
        float mean = s / 64.f, var = s2 / 64.f - mean * mean;
        float sc = P.hg[tid] * rsqrtf(var + EPS), sh = P.hb[tid] - mean * sc;
        for (int b = 0; b < 64; ++b){
            float v = f[tid * 64 + b] * sc + sh;
            f[tid * 64 + b] = v > 0.f ? v : 0.f;
        }
    }
    __syncthreads();
    if (tid < 64){
        int b = tid;
        float l[16];
        float m = -1e30f;
        for (int o = 0; o < 16; ++o){
            float a = P.lb[o];
            for (int ch = 0; ch < 46; ++ch) a += f[ch * 64 + b] * P.lw[o * 46 + ch];
            l[o] = a; m = fmaxf(m, a);
        }
        float se = 0.f;
        for (int o = 0; o < 16; ++o){ l[o] = expf(l[o] - m); se += l[o]; }
        float inv = 1.f / se;
        for (int o = 0; o < 16; ++o) P.out[b * 16 + o] = l[o] * inv;
    }
}

// ---------------------------------------------------------------------------
// The megakernel: 13 phases, 12 grid barriers.
// ---------------------------------------------------------------------------
__global__ __launch_bounds__(NTHR, 2)
void meganet(Params P)
{
    __shared__ float sm[10384];
    int* cnt = P.bar_cnt;

    float* st_t0 = P.stats;
    float* s_tloc = P.stats + 810;
    float* s_tglb = P.stats + 1014;
    float* s_t3 = P.stats + 1218;
    float* s_o3 = P.stats + 1422;
    float* s_t4 = P.stats + 1830;
    float* s_o6 = P.stats + 1932;
    float* s_t5 = P.stats + 2136;
    float* s_o9 = P.stats + 2186;

    // Phase 0: b1.conv1(bi0) ; b2.conv loc+glb
    for (int s = 0; s < 3; ++s)
        dv_conv(P.x, P.blk_w1 + s * 450, P.t_raw + s * 216000, st_t0 + s * 30, 30, 15, 225);
    dv_conv(P.y, P.loc_w1, P.t_loc, s_tloc, 204, 102, 9);
    dv_conv(P.y, P.glb_w1, P.t_glb, s_tglb, 204, 102, 9);
    grid_barrier(cnt, 1);
    // Phase 1: b1.invol(bi0) ; b2.crossatt
    dv_invol_b1(P, P.x, 0, sm);
    dv_crossatt(P, sm);
    grid_barrier(cnt, 2);
    // Phase 2: b1.blockend(bi0) x->bufA ; b2.conv c3
    dv_blockend(P, 0, P.x, P.bufA, sm);
    dv_conv(P.o_idn, P.c3_w1, P.t3, s_t3, 204, 102, 9);
    grid_barrier(cnt, 3);
    // Phase 3: b1.conv1(bi1) ; b2.invol3 c3
    for (int s = 0; s < 3; ++s)
        dv_conv(P.bufA, P.blk_w1 + 1350 + s * 450, P.t_raw + s * 216000, st_t0 + 90 + s * 30, 30, 15, 225);
    dv_invol3(P.o_idn, P.t3, s_t3, P.c3_g, P.c3_b, P.c3_w2, P.o3, s_o3, 204, 102, sm);
    grid_barrier(cnt, 4);
    // Phase 4: b1.invol(bi1) ; b2.bnconv p1 -> o5
    dv_invol_b1(P, P.bufA, 1, sm);
    dv_bnconv(P.o3, s_o3, P.bn1g, P.bn1b, P.o_idn, P.p1, P.o5, 204, 102, sm + 4800);
    grid_barrier(cnt, 5);
    // Phase 5: b1.blockend(bi1) bufA->bufB ; b2.conv c4
    dv_blockend(P, 1, P.bufA, P.bufB, sm);
    dv_conv(P.o5, P.c4_w1, P.t4, s_t4, 102, 51, 9);
    grid_barrier(cnt, 6);
    // Phase 6: b1.conv1(bi2) ; b2.invol3 c4
    for (int s = 0; s < 3; ++s)
        dv_conv(P.bufB, P.blk_w1 + 2700 + s * 450, P.t_raw + s * 216000, st_t0 + 180 + s * 30, 30, 15, 225);
    dv_invol3(P.o5, P.t4, s_t4, P.c4_g, P.c4_b, P.c4_w2, P.o6, s_o6, 102, 51, sm);
    grid_barrier(cnt, 7);
    // Phase 7: b1.invol(bi2) ; b2.bnconv p2 -> o8
    dv_invol_b1(P, P.bufB, 2, sm);
    dv_bnconv(P.o6, s_o6, P.bn2g, P.bn2b, nullptr, P.p2, P.o8, 102, 51, sm + 4800);
    grid_barrier(cnt, 8);
    // Phase 8: b1.blockend(bi2) bufB->bufA ; b2.conv c5
    dv_blockend(P, 2, P.bufB, P.bufA, sm);
    dv_conv(P.o8, P.c5_w1, P.t5, s_t5, 51, 25, 9);
    grid_barrier(cnt, 9);
    // Phase 9: b2.invol3 c5 ; b1.covpool30 (sequential per block, sm reused)
    dv_invol3(P.o8, P.t5, s_t5, P.c5_g, P.c5_b, P.c5_w2, P.o9, s_o9, 51, 25, sm);
    dv_covpool<30, 225>(P.bufA, P.feat1, sm);
    grid_barrier(cnt, 10);
    // Phase 10: b2.bnconv p3 -> o11
    dv_bnconv(P.o9, s_o9, P.bn3g, P.bn3b, P.o8, P.p3, P.o11, 51, 16, sm);
    grid_barrier(cnt, 11);
    // Phase 11: b2.covpool16
    dv_covpool<16, 9>(P.o11, P.feat2, sm);
    grid_barrier(cnt, 12);
    // Phase 12: head
    dv_head(P, sm);
}

extern "C" void kernel_launch(void* const* d_in, const int* in_sizes, int n_in,
                              void* d_out, int out_size, void* d_ws, size_t ws_size,
                              hipStream_t stream)
{
    (void)in_sizes; (void)n_in; (void)out_size; (void)ws_size;
    Params P;
    P.x = (const float*)d_in[0];   P.y = (const float*)d_in[1];
    P.blk_w1 = (const float*)d_in[2]; P.blk_ig = (const float*)d_in[3]; P.blk_ib = (const float*)d_in[4];
    P.blk_w2_5 = (const float*)d_in[5]; P.blk_w2_7 = (const float*)d_in[6]; P.blk_w2_9 = (const float*)d_in[7];
    P.blk_g = (const float*)d_in[8]; P.blk_b = (const float*)d_in[9]; P.blk_conv = (const float*)d_in[10];
    P.loc_w1 = (const float*)d_in[11]; P.loc_g = (const float*)d_in[12]; P.loc_b = (const float*)d_in[13]; P.loc_w2 = (const float*)d_in[14];
    P.glb_w1 = (const float*)d_in[15]; P.glb_g = (const float*)d_in[16]; P.glb_b = (const float*)d_in[17]; P.glb_w2 = (const float*)d_in[18];
    P.c3_w1 = (const float*)d_in[19]; P.c3_g = (const float*)d_in[20]; P.c3_b = (const float*)d_in[21]; P.c3_w2 = (const float*)d_in[22];
    P.c4_w1 = (const float*)d_in[23]; P.c4_g = (const float*)d_in[24]; P.c4_b = (const float*)d_in[25]; P.c4_w2 = (const float*)d_in[26];
    P.c5_w1 = (const float*)d_in[27]; P.c5_g = (const float*)d_in[28]; P.c5_b = (const float*)d_in[29]; P.c5_w2 = (const float*)d_in[30];
    P.p1 = (const float*)d_in[31]; P.p2 = (const float*)d_in[32]; P.p3 = (const float*)d_in[33];
    P.bn1g = (const float*)d_in[34]; P.bn1b = (const float*)d_in[35];
    P.bn2g = (const float*)d_in[36]; P.bn2b = (const float*)d_in[37];
    P.bn3g = (const float*)d_in[38]; P.bn3b = (const float*)d_in[39];
    P.hg = (const float*)d_in[40]; P.hb = (const float*)d_in[41];
    P.lw = (const float*)d_in[42]; P.lb = (const float*)d_in[43];
    P.out = (float*)d_out;

    float* ws = (float*)d_ws;
    size_t off = 0;
    auto alloc = [&](size_t n){ float* p = ws + off; off += n; return p; };
    P.bufA  = alloc(432000);
    P.bufB  = alloc(432000);
    P.t_raw = alloc(648000);
    P.o_raw = alloc(1296000);
    P.t_loc = alloc(58752);
    P.t_glb = alloc(58752);
    P.o_idn = alloc(117504);
    P.t3    = alloc(58752);
    P.o3    = alloc(117504);
    P.o5    = alloc(58752);
    P.t4    = alloc(29376);
    P.o6    = alloc(58752);
    P.o8    = alloc(29376);
    P.t5    = alloc(14400);
    P.o9    = alloc(29376);
    P.o11   = alloc(9216);
    P.feat1 = alloc(1920);
    P.feat2 = alloc(1024);
    P.stats = alloc(2288);
    float* barmem = alloc(4);
    P.bar_cnt = (int*)barmem;

    // zero stats + barrier counter (d_ws is poisoned 0xAA before every call)
    hipMemsetAsync(P.stats, 0, (2288 + 4) * sizeof(float), stream);

    meganet<<<NBLK, NTHR, 0, stream>>>(P);
}

// Round 11
// 1366.694 us; speedup vs baseline: 2.5997x; 1.2061x over previous
//
#include <hip/hip_runtime.h>
#include <math.h>

#define EPS 1e-5f
#define NBLK 128
#define NTHR 1024

// per-batch strides, padded to 16 floats (64 B) to avoid cross-XCD false sharing
#define TS1  3376   // 15*225 -> padded
#define BS1  6752   // 30*225 -> padded
#define S204 1840   // 204*9
#define S102 928    // 102*9
#define S51  464    // 51*9
#define S25  240    // 25*9
#define S16  144    // 16*9 (already 16-mult)

struct Params {
    const float *x, *y;
    const float *blk_w1, *blk_ig, *blk_ib, *blk_w2_5, *blk_w2_7, *blk_w2_9;
    const float *blk_g, *blk_b, *blk_conv;
    const float *loc_w1, *loc_g, *loc_b, *loc_w2;
    const float *glb_w1, *glb_g, *glb_b, *glb_w2;
    const float *c3_w1, *c3_g, *c3_b, *c3_w2;
    const float *c4_w1, *c4_g, *c4_b, *c4_w2;
    const float *c5_w1, *c5_g, *c5_b, *c5_w2;
    const float *p1, *p2, *p3;
    const float *bn1g, *bn1b, *bn2g, *bn2b, *bn3g, *bn3b;
    const float *hg, *hb, *lw, *lb;
    float *out;
    float *bufA, *bufB, *t_raw, *o_raw;
    float *t_loc, *t_glb, *o_idn, *t3, *o3, *o5, *t4, *o6, *o8, *t5, *o9, *o11;
    float *feat1, *feat2, *stats;
    int *bar_cnt;
};

__device__ inline void wave_red2(float& s1, float& s2){
    for (int off = 32; off; off >>= 1){
        s1 += __shfl_down(s1, off, 64);
        s2 += __shfl_down(s2, off, 64);
    }
}

// coherent-point accessors: per-access L1/L2 bypass, NO cache-wide invalidate
__device__ inline float ld_coh(const float* p){
    return __hip_atomic_load(p, __ATOMIC_RELAXED, __HIP_MEMORY_SCOPE_AGENT);
}
__device__ inline void st_coh(float* p, float v){
    __hip_atomic_store(p, v, __ATOMIC_RELAXED, __HIP_MEMORY_SCOPE_AGENT);
}

// Grid barrier k (k=1,2,...): monotonic counter, RELEASE arrival (orders the
// phase's device-scope atomicAdds), RELAXED spin, NO acquire fence -- all bulk
// data is block-local (same CU), cross-block data goes through atomics only.
__device__ inline void gbar(int* cnt, int k){
    __syncthreads();
    if (threadIdx.x == 0){
        __hip_atomic_fetch_add(cnt, 1, __ATOMIC_RELEASE, __HIP_MEMORY_SCOPE_AGENT);
        int target = NBLK * k;
        while (__hip_atomic_load(cnt, __ATOMIC_RELAXED, __HIP_MEMORY_SCOPE_AGENT) < target){
            __builtin_amdgcn_s_sleep(8);
        }
    }
    __syncthreads();
}

// ---------------------------------------------------------------------------
// Branch-1: conv1 (30->15, x3 involution sizes) for one batch. Stats global.
// ---------------------------------------------------------------------------
__device__ void b1_conv1(const float* __restrict__ cur_b, const float* __restrict__ w1,
                         float* __restrict__ t_raw, int b, float* __restrict__ st,
                         float* sm)
{
    float* cur_s = sm;   // 6750
    __syncthreads();
    for (int i = threadIdx.x; i < 6750; i += NTHR) cur_s[i] = cur_b[i];
    __syncthreads();
    for (int task = threadIdx.x; task < 45 * 256; task += NTHR){
        int u = task >> 8;          // s*15+j, wave-uniform
        int p = task & 255;
        bool act = p < 225;
        int pp = act ? p : 224;
        int s = u / 15, j = u - s * 15;
        const float* wr = w1 + (size_t)u * 30;   // uniform -> scalar loads
        float acc = 0.f;
        #pragma unroll
        for (int c = 0; c < 30; ++c) acc += cur_s[c * 225 + pp] * wr[c];
        float val = act ? acc : 0.f;
        if (act) t_raw[(size_t)s * 64 * TS1 + (size_t)b * TS1 + j * 225 + p] = val;
        float s1 = val, s2 = val * val;
        wave_red2(s1, s2);
        if ((threadIdx.x & 63) == 0){
            atomicAdd(&st[s * 30 + j], s1);
            atomicAdd(&st[s * 30 + 15 + j], s2);
        }
    }
}

// ---------------------------------------------------------------------------
// Branch-1: all three involutions (K=5,7,9, both groups) for one batch.
// ---------------------------------------------------------------------------
__device__ void b1_invol(const Params& P, const float* __restrict__ cur_b, int bi, int b,
                         float* sm)
{
    float* cur_s = sm;            // 6750
    float* w2s   = sm + 6752;     // 4650 (750 + 1470 + 2430)
    float* scb   = sm + 6752 + 4656;   // 45
    float* shb   = scb + 48;           // 45
    __syncthreads();
    for (int i = threadIdx.x; i < 6750; i += NTHR) cur_s[i] = cur_b[i];
    {
        const float* a = P.blk_w2_5 + bi * 750;
        const float* c = P.blk_w2_7 + bi * 1470;
        const float* d = P.blk_w2_9 + bi * 2430;
        for (int i = threadIdx.x; i < 750; i += NTHR)  w2s[i] = a[i];
        for (int i = threadIdx.x; i < 1470; i += NTHR) w2s[750 + i] = c[i];
        for (int i = threadIdx.x; i < 2430; i += NTHR) w2s[2220 + i] = d[i];
    }
    const float* st_t = P.stats + bi * 90;
    if (threadIdx.x < 45){
        int s = threadIdx.x / 15, j = threadIdx.x - s * 15;
        float sum = ld_coh(&st_t[s * 30 + j]);
        float sq  = ld_coh(&st_t[s * 30 + 15 + j]);
        const float invN = 1.f / 14400.f;
        float mean = sum * invN, var = sq * invN - mean * mean;
        float sc = P.blk_ig[bi * 45 + threadIdx.x] * rsqrtf(var + EPS);
        scb[threadIdx.x] = sc;
        shb[threadIdx.x] = P.blk_ib[bi * 45 + threadIdx.x] - mean * sc;
    }
    __syncthreads();
    float* st_o = P.stats + 270 + bi * 180;
    for (int task = threadIdx.x; task < 6 * 256; task += NTHR){
        int u = task >> 8;          // ks*2+g, wave-uniform
        int p = task & 255;
        bool act = p < 225;
        int pp = act ? p : 224;
        int ks = u >> 1, g = u & 1;
        int K = 5 + 2 * ks;
        int KK = K * K;
        int Pp = ks + 2;
        int w2off = (ks == 0) ? 0 : (ks == 1 ? 750 : 2220);
        int h = pp / 15, w = pp - h * 15;
        const float* trb = P.t_raw + (size_t)ks * 64 * TS1 + (size_t)b * TS1 + pp;
        float treg[15];
        #pragma unroll
        for (int j = 0; j < 15; ++j){
            float v = trb[j * 225] * scb[ks * 15 + j] + shb[ks * 15 + j];
            treg[j] = v > 0.f ? v : 0.f;
        }
        const float* wloc = w2s + w2off + g * KK * 15;
        float acc[15];
        #pragma unroll
        for (int cc = 0; cc < 15; ++cc) acc[cc] = 0.f;
        int ki = 0, kj = 0;
        #pragma unroll 1
        for (int kk = 0; kk < KK; ++kk){
            int hh = h + ki - Pp, ww = w + kj - Pp;
            bool ok = ((unsigned)hh < 15u) && ((unsigned)ww < 15u);
            const float* wr = wloc + kk * 15;
            float wkv = 0.f;
            #pragma unroll
            for (int j = 0; j < 15; ++j) wkv += treg[j] * wr[j];
            float sc2 = ok ? wkv : 0.f;
            int offr = ok ? hh * 15 + ww : 0;
            const float* cs = cur_s + g * 3375 + offr;
            #pragma unroll
            for (int cc = 0; cc < 15; ++cc) acc[cc] += sc2 * cs[cc * 225];
            ++kj; if (kj == K){ kj = 0; ++ki; }
        }
        float* ob = P.o_raw + (size_t)ks * 64 * BS1 + (size_t)b * BS1 + (size_t)g * 3375;
        #pragma unroll 1
        for (int cc = 0; cc < 15; ++cc){
            float val = act ? acc[cc] : 0.f;
            if (act) ob[cc * 225 + pp] = val;
            float s1 = val, s2 = val * val;
            wave_red2(s1, s2);
            if ((threadIdx.x & 63) == 0){
                // FIX R10->R11: per-involution stats region offset ks*60
                atomicAdd(&st_o[ks * 60 + g * 15 + cc], s1);
                atomicAdd(&st_o[ks * 60 + 30 + g * 15 + cc], s2);
            }
        }
    }
}

// ---------------------------------------------------------------------------
// Branch-1: block end for one batch.
// ---------------------------------------------------------------------------
__device__ void b1_blockend(const Params& P, int bi, int b,
                            const float* __restrict__ old_b, float* __restrict__ new_b,
                            float* sm)
{
    float* conv_s = sm;            // 2700
    float* sc = sm + 2704;         // 90
    float* sh = sm + 2800;         // 90
    __syncthreads();
    const float* conv = P.blk_conv + bi * 2700;
    for (int i = threadIdx.x; i < 2700; i += NTHR) conv_s[i] = conv[i];
    const float* st_o = P.stats + 270 + bi * 180;
    if (threadIdx.x < 90){
        int ii = threadIdx.x / 30, cc = threadIdx.x - ii * 30;
        float sum = ld_coh(&st_o[ii * 60 + cc]);
        float sq  = ld_coh(&st_o[ii * 60 + 30 + cc]);
        const float invN = 1.f / 14400.f;
        float mean = sum * invN, var = sq * invN - mean * mean;
        float s = P.blk_g[bi * 90 + threadIdx.x] * rsqrtf(var + EPS);
        sc[threadIdx.x] = s;
        sh[threadIdx.x] = P.blk_b[bi * 90 + threadIdx.x] - mean * s;
    }
    __syncthreads();
    for (int t = threadIdx.x; t < 6750; t += NTHR){
        int c = t / 225, p = t - c * 225;
        float acc = old_b[c * 225 + p];
        const float* cr = conv_s + c * 90;
        #pragma unroll
        for (int ii = 0; ii < 3; ++ii){
            const float* op = P.o_raw + (size_t)ii * 64 * BS1 + (size_t)b * BS1 + p;
            #pragma unroll 6
            for (int cc = 0; cc < 30; ++cc){
                float v = op[cc * 225] * sc[ii * 30 + cc] + sh[ii * 30 + cc];
                v = v > 0.f ? v : 0.f;
                acc += v * cr[ii * 30 + cc];
            }
        }
        new_b[c * 225 + p] = acc;
    }
}

// ---------------------------------------------------------------------------
// GlobalCovPooling for one batch (block-local). Faithful incl. ELEMENTWISE
// Y-update. feat written via coherent stores (read cross-block by head).
// ---------------------------------------------------------------------------
template<int C, int N>
__device__ void covpool_b(const float* __restrict__ in_b, float* __restrict__ feat, int b,
                          float* sm)
{
    constexpr int CC = C * C;
    float* X = sm;
    float* Ybuf = sm + N * C;
    float* Mbuf = Ybuf + CC;
    float* Zbuf = Mbuf + CC;
    float* Z2buf = Zbuf + CC;
    float* mu = Z2buf + CC;
    float* scal = mu + C;
    int tid = threadIdx.x;
    __syncthreads();
    for (int i = tid; i < N * C; i += NTHR){
        int n = i / C, c = i - n * C;
        X[i] = in_b[(size_t)c * N + n];
    }
    __syncthreads();
    if (tid < C){
        float s = 0.f;
        #pragma unroll 5
        for (int n = 0; n < N; ++n) s += X[n * C + tid];
        mu[tid] = s / (float)N;
    }
    __syncthreads();
    for (int i = tid; i < CC; i += NTHR){
        int c = i / C, d = i - c * C;
        float s = 0.f;
        #pragma unroll 5
        for (int n = 0; n < N; ++n) s += X[n * C + c] * X[n * C + d];
        Ybuf[i] = s / (float)N - mu[c] * mu[d];
    }
    __syncthreads();
    if (tid == 0){
        float tr = 0.f;
        for (int c = 0; c < C; ++c) tr += Ybuf[c * C + c];
        scal[0] = 1.f / tr;
    }
    __syncthreads();
    for (int i = tid; i < CC; i += NTHR){
        int c = i / C, d = i - c * C;
        Ybuf[i] *= scal[0];
        Zbuf[i] = (c == d) ? 1.f : 0.f;
    }
    __syncthreads();
    float* zs = Zbuf; float* zd = Z2buf;
    for (int it = 0; it < 6; ++it){
        for (int i = tid; i < CC; i += NTHR){
            int c = i / C, d = i - c * C;
            float s = 0.f;
            #pragma unroll 6
            for (int e = 0; e < C; ++e) s += zs[c * C + e] * Ybuf[e * C + d];
            Mbuf[i] = ((c == d) ? 3.f : 0.f) - s;
        }
        __syncthreads();
        for (int i = tid; i < CC; i += NTHR){
            int c = i / C, d = i - c * C;
            float s = 0.f;
            #pragma unroll 6
            for (int e = 0; e < C; ++e) s += Mbuf[c * C + e] * zs[e * C + d];
            zd[i] = 0.5f * s;
        }
        for (int i = tid; i < CC; i += NTHR) Ybuf[i] *= 0.5f * Mbuf[i];   // elementwise, as in source
        __syncthreads();
        float* t = zs; zs = zd; zd = t;
    }
    if (tid == 0){
        float tr = 0.f;
        for (int c = 0; c < C; ++c) tr += Ybuf[c * C + c];
        scal[1] = sqrtf(tr);
    }
    __syncthreads();
    if (tid < C){
        float s = 0.f;
        #pragma unroll 6
        for (int c = 0; c < C; ++c) s += Ybuf[c * C + tid];
        st_coh(&feat[(size_t)b * C + tid], scal[1] * s / (float)C);
    }
}

// ---------------------------------------------------------------------------
// Branch-2: conv1x1 (per batch) with stats via LDS partials.
// ---------------------------------------------------------------------------
__device__ void b2_conv(const float* __restrict__ in_b, const float* __restrict__ w,
                        float* __restrict__ out_b, float* __restrict__ st,
                        int Cin, int Cout, float* sm)
{
    float* ls = sm;            // 2*Cout <= 408
    float* in_s = sm + 512;    // Cin*9 <= 1836
    __syncthreads();
    for (int i = threadIdx.x; i < 2 * Cout; i += NTHR) ls[i] = 0.f;
    for (int i = threadIdx.x; i < Cin * 9; i += NTHR) in_s[i] = in_b[i];
    __syncthreads();
    for (int t = threadIdx.x; t < Cout * 9; t += NTHR){
        int j = t / 9, pos = t - j * 9;
        const float* wr = w + (size_t)j * Cin;
        float acc = 0.f;
        #pragma unroll 4
        for (int c = 0; c < Cin; ++c) acc += in_s[c * 9 + pos] * wr[c];
        out_b[j * 9 + pos] = acc;
        atomicAdd(&ls[j], acc);
        atomicAdd(&ls[Cout + j], acc * acc);
    }
    __syncthreads();
    for (int i = threadIdx.x; i < 2 * Cout; i += NTHR) atomicAdd(&st[i], ls[i]);
}

// ---------------------------------------------------------------------------
// Branch-2: cross-attention front for one batch: o_idn = y * (loc + glb).
// ---------------------------------------------------------------------------
__device__ void b2_crossatt(const Params& P, int b, float* sm)
{
    float* lsc = sm;          float* lsh = sm + 102;
    float* gsc = sm + 204;    float* gsh = sm + 306;
    float* y_s = sm + 512;    // 1836
    float* tl_s = sm + 2368;  // 918 (BN+ReLU'd)
    float* tg_s = sm + 3296;  // 918
    float* gw_s = sm + 4224;  // 918
    __syncthreads();
    const float* s_tloc = P.stats + 810;
    const float* s_tglb = P.stats + 1014;
    const float invN = 1.f / 576.f;
    if (threadIdx.x < 102){
        int j = threadIdx.x;
        float m1 = ld_coh(&s_tloc[j]) * invN;
        float v1 = ld_coh(&s_tloc[102 + j]) * invN - m1 * m1;
        float a1 = P.loc_g[j] * rsqrtf(v1 + EPS);
        lsc[j] = a1; lsh[j] = P.loc_b[j] - m1 * a1;
        float m2 = ld_coh(&s_tglb[j]) * invN;
        float v2 = ld_coh(&s_tglb[102 + j]) * invN - m2 * m2;
        float a2 = P.glb_g[j] * rsqrtf(v2 + EPS);
        gsc[j] = a2; gsh[j] = P.glb_b[j] - m2 * a2;
    }
    const float* yb = P.y + (size_t)b * 1836;
    for (int i = threadIdx.x; i < 1836; i += NTHR) y_s[i] = yb[i];
    for (int i = threadIdx.x; i < 918; i += NTHR) gw_s[i] = P.glb_w2[i];
    __syncthreads();
    const float* tlb = P.t_loc + (size_t)b * S102;
    const float* tgb = P.t_glb + (size_t)b * S102;
    for (int i = threadIdx.x; i < 918; i += NTHR){
        int j = i / 9;
        float a = tlb[i] * lsc[j] + lsh[j];
        tl_s[i] = a > 0.f ? a : 0.f;
        float g2 = tgb[i] * gsc[j] + gsh[j];
        tg_s[i] = g2 > 0.f ? g2 : 0.f;
    }
    __syncthreads();
    float* ob = P.o_idn + (size_t)b * S204;
    for (int t = threadIdx.x; t < 1836; t += NTHR){
        int c = t / 9, hw = t - c * 9;
        int h = hw / 3, w = hw - h * 3;
        const float* wl = P.loc_w2 + (size_t)c * 918;
        float wk[9];
        #pragma unroll
        for (int kk = 0; kk < 9; ++kk) wk[kk] = 0.f;
        #pragma unroll 1
        for (int j = 0; j < 102; ++j){
            float a = tl_s[j * 9 + hw];
            float g2 = tg_s[j * 9 + hw];
            #pragma unroll
            for (int kk = 0; kk < 9; ++kk)
                wk[kk] += a * wl[kk * 102 + j] + g2 * gw_s[kk * 102 + j];
        }
        const float* pb = y_s + c * 9;
        float acc = 0.f;
        #pragma unroll
        for (int ki = 0; ki < 3; ++ki){
            int hh = h + ki - 1;
            bool hok = (unsigned)hh < 3u;
            #pragma unroll
            for (int kj = 0; kj < 3; ++kj){
                int ww = w + kj - 1;
                bool ok = hok && ((unsigned)ww < 3u);
                float v = ok ? pb[hh * 3 + ww] : 0.f;
                acc += wk[ki * 3 + kj] * v;
            }
        }
        ob[t] = pb[hw] * acc;
    }
}

// ---------------------------------------------------------------------------
// Branch-2: groups==1 involution (k=3) for one batch, with stats.
// ---------------------------------------------------------------------------
__device__ void b2_invol3(const float* __restrict__ in_b, const float* __restrict__ t_b,
                          const float* __restrict__ st_t,
                          const float* __restrict__ tg, const float* __restrict__ tb,
                          const float* __restrict__ w2,
                          float* __restrict__ out_b, float* __restrict__ st_o,
                          int C, int Ct, float* sm)
{
    float* tsc = sm;            // <=102
    float* tsh = sm + 128;
    float* t_s = sm + 256;      // Ct*9 <= 918 (BN+ReLU'd)
    float* w2s = sm + 1280;     // 9*Ct <= 918
    float* in_s = sm + 2304;    // C*9 <= 1836
    float* ls = sm + 4160;      // 2C <= 408
    __syncthreads();
    const float invN = 1.f / 576.f;
    if (threadIdx.x < Ct){
        int j = threadIdx.x;
        float mean = ld_coh(&st_t[j]) * invN;
        float var  = ld_coh(&st_t[Ct + j]) * invN - mean * mean;
        float s = tg[j] * rsqrtf(var + EPS);
        tsc[j] = s; tsh[j] = tb[j] - mean * s;
    }
    for (int i = threadIdx.x; i < 9 * Ct; i += NTHR) w2s[i] = w2[i];
    for (int i = threadIdx.x; i < C * 9; i += NTHR) in_s[i] = in_b[i];
    for (int i = threadIdx.x; i < 2 * C; i += NTHR) ls[i] = 0.f;
    __syncthreads();
    for (int i = threadIdx.x; i < Ct * 9; i += NTHR){
        int j = i / 9;
        float t = t_b[i] * tsc[j] + tsh[j];
        t_s[i] = t > 0.f ? t : 0.f;
    }
    __syncthreads();
    for (int t = threadIdx.x; t < C * 9; t += NTHR){
        int c = t / 9, hw = t - c * 9;
        int h = hw / 3, w = hw - h * 3;
        float wk[9];
        #pragma unroll
        for (int kk = 0; kk < 9; ++kk) wk[kk] = 0.f;
        #pragma unroll 1
        for (int j = 0; j < Ct; ++j){
            float tv = t_s[j * 9 + hw];
            #pragma unroll
            for (int kk = 0; kk < 9; ++kk) wk[kk] += tv * w2s[kk * Ct + j];
        }
        const float* pb = in_s + c * 9;
        float acc = 0.f;
        #pragma unroll
        for (int ki = 0; ki < 3; ++ki){
            int hh = h + ki - 1;
            bool hok = (unsigned)hh < 3u;
            #pragma unroll
            for (int kj = 0; kj < 3; ++kj){
                int ww = w + kj - 1;
                bool ok = hok && ((unsigned)ww < 3u);
                float v = ok ? pb[hh * 3 + ww] : 0.f;
                acc += wk[ki * 3 + kj] * v;
            }
        }
        out_b[t] = acc;
        atomicAdd(&ls[c], acc);
        atomicAdd(&ls[C + c], acc * acc);
    }
    __syncthreads();
    for (int i = threadIdx.x; i < 2 * C; i += NTHR) atomicAdd(&st_o[i], ls[i]);
}

// ---------------------------------------------------------------------------
// Branch-2: BN+ReLU(+residual) -> conv1x1 for one batch.
// ---------------------------------------------------------------------------
__device__ void b2_bnconv(const float* __restrict__ in_b, const float* __restrict__ st,
                          const float* __restrict__ g, const float* __restrict__ bta,
                          const float* __restrict__ idn_b, const float* __restrict__ w,
                          float* __restrict__ out_b, int Cin, int Cout, float* sm)
{
    float* sc = sm;            // <=204
    float* sh = sm + 256;
    float* f_s = sm + 512;     // Cin*9 <= 1836
    __syncthreads();
    const float invN = 1.f / 576.f;
    if (threadIdx.x < Cin){
        int j = threadIdx.x;
        float mean = ld_coh(&st[j]) * invN;
        float var = ld_coh(&st[Cin + j]) * invN - mean * mean;
        float s = g[j] * rsqrtf(var + EPS);
        sc[j] = s; sh[j] = bta[j] - mean * s;
    }
    __syncthreads();
    for (int i = threadIdx.x; i < Cin * 9; i += NTHR){
        int c = i / 9;
        float v = in_b[i] * sc[c] + sh[c];
        v = v > 0.f ? v : 0.f;
        if (idn_b) v += idn_b[i];
        f_s[i] = v;
    }
    __syncthreads();
    for (int t = threadIdx.x; t < Cout * 9; t += NTHR){
        int j = t / 9, pos = t - j * 9;
        const float* wr = w + (size_t)j * Cin;
        float acc = 0.f;
        #pragma unroll 4
        for (int c = 0; c < Cin; ++c) acc += f_s[c * 9 + pos] * wr[c];
        out_b[t] = acc;
    }
}

// ---------------------------------------------------------------------------
// Head (block 0): reads feats via coherent loads.
// ---------------------------------------------------------------------------
__device__ void dv_head(const Params& P, float* sm)
{
    float* f = sm;   // 46*64
    int tid = threadIdx.x;
    __syncthreads();
    for (int i = tid; i < 46 * 64; i += NTHR){
        int ch = i / 64, b = i - ch * 64;
        f[i] = ch < 30 ? ld_coh(&P.feat1[b * 30 + ch]) : ld_coh(&P.feat2[b * 16 + (ch - 30)]);
    }
    __syncthreads();
    if (tid < 46){
        float s = 0.f, s2 = 0.f;
        for (int b = 0; b < 64; ++b){ float v = f[tid * 64 + b]; s += v; s2 += v * v; }
        float mean = s / 64.f, var = s2 / 64.f - mean * mean;
        float sc = P.hg[tid] * rsqrtf(var + EPS), sh = P.hb[tid] - mean * sc;
        for (int b = 0; b < 64; ++b){
            float v = f[tid * 64 + b] * sc + sh;
            f[tid * 64 + b] = v > 0.f ? v : 0.f;
        }
    }
    __syncthreads();
    if (tid < 64){
        int b = tid;
        float l[16];
        float m = -1e30f;
        for (int o = 0; o < 16; ++o){
            float a = P.lb[o];
            for (int ch = 0; ch < 46; ++ch) a += f[ch * 64 + b] * P.lw[o * 46 + ch];
            l[o] = a; m = fmaxf(m, a);
        }
        float se = 0.f;
        for (int o = 0; o < 16; ++o){ l[o] = expf(l[o] - m); se += l[o]; }
        float inv = 1.f / se;
        for (int o = 0; o < 16; ++o) P.out[b * 16 + o] = l[o] * inv;
    }
}

// ---------------------------------------------------------------------------
// Megakernel v2: 128 persistent blocks. Block b<64 = branch-1 batch b;
// block 64+b = branch-2 batch b. All bulk data block-local (same-CU
// coherence); cross-block only via atomics. 8 barriers, no threadfence.
// ---------------------------------------------------------------------------
__global__ __launch_bounds__(NTHR, 1)
void meganet(Params P)
{
    __shared__ float sm[11520];
    int* cnt = P.bar_cnt;
    const bool isB1 = blockIdx.x < 64;
    const int b = isB1 ? (int)blockIdx.x : (int)blockIdx.x - 64;

    const float* x_b = P.x + (size_t)b * 6750;
    const float* y_b = P.y + (size_t)b * 1836;
    float* bufA_b = P.bufA + (size_t)b * BS1;
    float* bufB_b = P.bufB + (size_t)b * BS1;

    float* s_tloc = P.stats + 810;
    float* s_tglb = P.stats + 1014;
    float* s_t3 = P.stats + 1218;
    float* s_o3 = P.stats + 1422;
    float* s_t4 = P.stats + 1830;
    float* s_o6 = P.stats + 1932;
    float* s_t5 = P.stats + 2136;
    float* s_o9 = P.stats + 2186;

    float* tl_b = P.t_loc + (size_t)b * S102;
    float* tg_b = P.t_glb + (size_t)b * S102;
    float* oi_b = P.o_idn + (size_t)b * S204;
    float* t3_b = P.t3 + (size_t)b * S102;
    float* o3_b = P.o3 + (size_t)b * S204;
    float* o5_b = P.o5 + (size_t)b * S102;
    float* t4_b = P.t4 + (size_t)b * S51;
    float* o6_b = P.o6 + (size_t)b * S102;
    float* o8_b = P.o8 + (size_t)b * S51;
    float* t5_b = P.t5 + (size_t)b * S25;
    float* o9_b = P.o9 + (size_t)b * S51;
    float* o11_b = P.o11 + (size_t)b * S16;

    // Phase 0
    if (isB1){
        b1_conv1(x_b, P.blk_w1, P.t_raw, b, P.stats, sm);
    } else {
        b2_conv(y_b, P.loc_w1, tl_b, s_tloc, 204, 102, sm);
        b2_conv(y_b, P.glb_w1, tg_b, s_tglb, 204, 102, sm);
    }
    gbar(cnt, 1);
    // Phase 1
    if (isB1){
        b1_invol(P, x_b, 0, b, sm);
    } else {
        b2_crossatt(P, b, sm);
        b2_conv(oi_b, P.c3_w1, t3_b, s_t3, 204, 102, sm);
    }
    gbar(cnt, 2);
    // Phase 2
    if (isB1){
        b1_blockend(P, 0, b, x_b, bufA_b, sm);
        b1_conv1(bufA_b, P.blk_w1 + 1350, P.t_raw, b, P.stats + 90, sm);
    } else {
        b2_invol3(oi_b, t3_b, s_t3, P.c3_g, P.c3_b, P.c3_w2, o3_b, s_o3, 204, 102, sm);
    }
    gbar(cnt, 3);
    // Phase 3
    if (isB1){
        b1_invol(P, bufA_b, 1, b, sm);
    } else {
        b2_bnconv(o3_b, s_o3, P.bn1g, P.bn1b, oi_b, P.p1, o5_b, 204, 102, sm);
        b2_conv(o5_b, P.c4_w1, t4_b, s_t4, 102, 51, sm);
    }
    gbar(cnt, 4);
    // Phase 4
    if (isB1){
        b1_blockend(P, 1, b, bufA_b, bufB_b, sm);
        b1_conv1(bufB_b, P.blk_w1 + 2700, P.t_raw, b, P.stats + 180, sm);
    } else {
        b2_invol3(o5_b, t4_b, s_t4, P.c4_g, P.c4_b, P.c4_w2, o6_b, s_o6, 102, 51, sm);
    }
    gbar(cnt, 5);
    // Phase 5
    if (isB1){
        b1_invol(P, bufB_b, 2, b, sm);
    } else {
        b2_bnconv(o6_b, s_o6, P.bn2g, P.bn2b, nullptr, P.p2, o8_b, 102, 51, sm);
        b2_conv(o8_b, P.c5_w1, t5_b, s_t5, 51, 25, sm);
    }
    gbar(cnt, 6);
    // Phase 6
    if (isB1){
        b1_blockend(P, 2, b, bufB_b, bufA_b, sm);
        covpool_b<30, 225>(bufA_b, P.feat1, b, sm);
    } else {
        b2_invol3(o8_b, t5_b, s_t5, P.c5_g, P.c5_b, P.c5_w2, o9_b, s_o9, 51, 25, sm);
    }
    gbar(cnt, 7);
    // Phase 7
    if (!isB1){
        b2_bnconv(o9_b, s_o9, P.bn3g, P.bn3b, o8_b, P.p3, o11_b, 51, 16, sm);
        covpool_b<16, 9>(o11_b, P.feat2, b, sm);
    }
    gbar(cnt, 8);
    // Phase 8
    if (blockIdx.x == 0) dv_head(P, sm);
}

extern "C" void kernel_launch(void* const* d_in, const int* in_sizes, int n_in,
                              void* d_out, int out_size, void* d_ws, size_t ws_size,
                              hipStream_t stream)
{
    (void)in_sizes; (void)n_in; (void)out_size; (void)ws_size;
    Params P;
    P.x = (const float*)d_in[0];   P.y = (const float*)d_in[1];
    P.blk_w1 = (const float*)d_in[2]; P.blk_ig = (const float*)d_in[3]; P.blk_ib = (const float*)d_in[4];
    P.blk_w2_5 = (const float*)d_in[5]; P.blk_w2_7 = (const float*)d_in[6]; P.blk_w2_9 = (const float*)d_in[7];
    P.blk_g = (const float*)d_in[8]; P.blk_b = (const float*)d_in[9]; P.blk_conv = (const float*)d_in[10];
    P.loc_w1 = (const float*)d_in[11]; P.loc_g = (const float*)d_in[12]; P.loc_b = (const float*)d_in[13]; P.loc_w2 = (const float*)d_in[14];
    P.glb_w1 = (const float*)d_in[15]; P.glb_g = (const float*)d_in[16]; P.glb_b = (const float*)d_in[17]; P.glb_w2 = (const float*)d_in[18];
    P.c3_w1 = (const float*)d_in[19]; P.c3_g = (const float*)d_in[20]; P.c3_b = (const float*)d_in[21]; P.c3_w2 = (const float*)d_in[22];
    P.c4_w1 = (const float*)d_in[23]; P.c4_g = (const float*)d_in[24]; P.c4_b = (const float*)d_in[25]; P.c4_w2 = (const float*)d_in[26];
    P.c5_w1 = (const float*)d_in[27]; P.c5_g = (const float*)d_in[28]; P.c5_b = (const float*)d_in[29]; P.c5_w2 = (const float*)d_in[30];
    P.p1 = (const float*)d_in[31]; P.p2 = (const float*)d_in[32]; P.p3 = (const float*)d_in[33];
    P.bn1g = (const float*)d_in[34]; P.bn1b = (const float*)d_in[35];
    P.bn2g = (const float*)d_in[36]; P.bn2b = (const float*)d_in[37];
    P.bn3g = (const float*)d_in[38]; P.bn3b = (const float*)d_in[39];
    P.hg = (const float*)d_in[40]; P.hb = (const float*)d_in[41];
    P.lw = (const float*)d_in[42]; P.lb = (const float*)d_in[43];
    P.out = (float*)d_out;

    float* ws = (float*)d_ws;
    size_t off = 0;
    auto alloc = [&](size_t n){ float* p = ws + off; off += n; return p; };
    P.bufA  = alloc(64 * BS1);
    P.bufB  = alloc(64 * BS1);
    P.t_raw = alloc(3 * 64 * TS1);
    P.o_raw = alloc((size_t)3 * 64 * BS1);
    P.t_loc = alloc(64 * S102);
    P.t_glb = alloc(64 * S102);
    P.o_idn = alloc(64 * S204);
    P.t3    = alloc(64 * S102);
    P.o3    = alloc(64 * S204);
    P.o5    = alloc(64 * S102);
    P.t4    = alloc(64 * S51);
    P.o6    = alloc(64 * S102);
    P.o8    = alloc(64 * S51);
    P.t5    = alloc(64 * S25);
    P.o9    = alloc(64 * S51);
    P.o11   = alloc(64 * S16);
    P.feat1 = alloc(1920);
    P.feat2 = alloc(1024);
    P.stats = alloc(2288);
    float* barmem = alloc(16);
    P.bar_cnt = (int*)barmem;

    // zero stats + barrier counter (d_ws is poisoned 0xAA before every call)
    hipMemsetAsync(P.stats, 0, (2288 + 16) * sizeof(float), stream);

    meganet<<<NBLK, NTHR, 0, stream>>>(P);
}